// Round 5
// baseline (147.128 us; speedup 1.0000x reference)
//
#include <hip/hip_runtime.h>
#include <hip/hip_bf16.h>

// ILA layer (all fp32): key = W@ft, query = W@fk (1x1 conv, shared W),
// sim[p,k] = <query[p], key[neighbor_k(p)]> over 9x9 window (zero-padded keys),
// weight = softmax_k(sim)  (OOB entries participate with sim=0),
// out[c,p] = sum_k weight[k] * ft[c, neighbor_k(p)]  (zero-padded ft).
// n=2, c=128, h=w=64, L=9 (81 neighbors).

#define Hh 64
#define Ww 64
#define Cc 128
#define Nn 2
#define KK 81
#define HW (Hh * Ww)          // 4096
#define CHW (Cc * HW)         // 524288
#define P_TOT (Nn * HW)       // 8192

__device__ __forceinline__ void fma4(float4& a, const float4 b, const float s) {
    a.x += b.x * s; a.y += b.y * s; a.z += b.z * s; a.w += b.w * s;
}

// ---------------- Kernel A: projection (K = W*ft, Q = W*fk), pixel-major fp32 out.
// 512 blocks x 256 thr; 16 px/block; thread = 4 px x 2 out x {K,Q}.
__global__ __launch_bounds__(256) void proj_kernel(const float* __restrict__ ft,
                                                   const float* __restrict__ fk,
                                                   const float* __restrict__ Wm,
                                                   float* __restrict__ Qbuf,
                                                   float* __restrict__ Kbuf) {
    __shared__ __align__(16) float Wl[32 * 132];   // [ii][o] chunk of W^T
    __shared__ __align__(16) float xkl[128 * 20];  // [i][pl], pad 20
    __shared__ __align__(16) float xql[128 * 20];
    const int t = threadIdx.x;
    const int p0 = blockIdx.x * 16;       // 4096 % 16 == 0: never crosses n
    const int nn = p0 >> 12;
    const int gbase = nn * CHW + (p0 & 4095);

    for (int e = t; e < 128 * 16; e += 256) {       // stage x tiles (coalesced 64B runs)
        const int c = e >> 4, pl = e & 15;
        xkl[c * 20 + pl] = ft[gbase + c * HW + pl];
        xql[c * 20 + pl] = fk[gbase + c * HW + pl];
    }

    const int po = t & 3;                 // 4 pixel groups x 4 px
    const int oo = t >> 2;                // 64 out groups x 2 out
    float4 aK0 = make_float4(0,0,0,0), aK1 = aK0, aQ0 = aK0, aQ1 = aK0;

    for (int ch = 0; ch < 4; ++ch) {
        for (int e = t; e < 128 * 32; e += 256) {   // Wl[ii][o] <- Wm[o][ch*32+ii]
            const int o = e >> 5, ii = e & 31;
            Wl[ii * 132 + o] = Wm[o * 128 + (ch << 5) + ii];
        }
        __syncthreads();
#pragma unroll 8
        for (int ii = 0; ii < 32; ++ii) {
            const float2 w2 = *(const float2*)&Wl[ii * 132 + (oo << 1)];
            const float4 k4 = *(const float4*)&xkl[((ch << 5) + ii) * 20 + (po << 2)];
            const float4 q4 = *(const float4*)&xql[((ch << 5) + ii) * 20 + (po << 2)];
            fma4(aK0, k4, w2.x); fma4(aK1, k4, w2.y);
            fma4(aQ0, q4, w2.x); fma4(aQ1, q4, w2.y);
        }
        __syncthreads();
    }

    const float kx[4] = {aK0.x, aK0.y, aK0.z, aK0.w};
    const float ky[4] = {aK1.x, aK1.y, aK1.z, aK1.w};
    const float qx[4] = {aQ0.x, aQ0.y, aQ0.z, aQ0.w};
    const float qy[4] = {aQ1.x, aQ1.y, aQ1.z, aQ1.w};
#pragma unroll
    for (int pp = 0; pp < 4; ++pp) {
        const size_t base = (size_t)(p0 + (po << 2) + pp) * 128 + (oo << 1);
        *(float2*)&Kbuf[base] = make_float2(kx[pp], ky[pp]);
        *(float2*)&Qbuf[base] = make_float2(qx[pp], qy[pp]);
    }
}

// ---------------- Kernel B (fused): sim + softmax + weighting. Block = 8-px row strip.
// Phase 1: stage K (9x16 vectors, XOR-swizzled) + Q, dot products -> registers.
// Phase 2: register softmax via shfl_xor + one 32-float cross-wave exchange.
// Phase 3: restage ft into the (dead) Ksw space; weighted sum; scale by 1/s; store.
__global__ __launch_bounds__(256) void sim_weight_kernel(const float* __restrict__ Qbuf,
                                                         const float* __restrict__ Kbuf,
                                                         const float* __restrict__ ft,
                                                         float* __restrict__ out) {
    __shared__ __align__(16) float lds[20168];
    float* Ksw  = lds;            // 18432 floats (dead after dots)
    float* Qsw  = lds + 18432;    // 1024   (dead after dots)
    float* ftl  = lds;            // 18432  (aliases Ksw after B2)
    float* redM = lds + 19456;    // 32
    float* redS = lds + 19488;    // 32
    float* simb = lds + 19520;    // 648

    const int t  = threadIdx.x;
    const int b  = blockIdx.x;
    const int x0 = (b & 7) << 3;
    const int y  = (b >> 3) & 63;
    const int nn = b >> 9;
    const int pg0 = (nn << 12) + (y << 6) + x0;

    // ---- stage K: zero-padded 9x16 window, coalesced 512B runs per vector
    for (int e = t; e < 144 * 32; e += 256) {
        const int v = e >> 5, ci = e & 31;
        const int gx = x0 + (v & 15) - 4;
        const int gy = y + (v >> 4) - 4;
        float4 val = make_float4(0, 0, 0, 0);
        if ((unsigned)gx < 64u && (unsigned)gy < 64u)
            val = *(const float4*)&Kbuf[(size_t)((nn << 12) + (gy << 6) + gx) * 128 + (ci << 2)];
        *(float4*)&Ksw[(v << 7) + (((ci ^ (v & 31)) << 2))] = val;
    }
    {   // stage Q: 8 vectors, 256 threads = exactly 8*32 chunks
        const int v = t >> 5, ci = t & 31;
        const float4 val = *(const float4*)&Qbuf[(size_t)(pg0 + v) * 128 + (ci << 2)];
        *(float4*)&Qsw[(v << 7) + ((ci ^ v) << 2)] = val;
    }
    __syncthreads();   // B1

    // ---- dots: thread -> (pixel p, k in {kb, kb+32, kb+64})
    const int p = t & 7, kb = t >> 3;
    const bool has2 = (kb + 64 < KK);
    const int k0 = kb, k1 = kb + 32, k2 = has2 ? kb + 64 : kb;
    const int v0 = (k0 / 9) * 16 + p + k0 % 9;
    const int v1 = (k1 / 9) * 16 + p + k1 % 9;
    const int v2 = (k2 / 9) * 16 + p + k2 % 9;
    const int b0 = v0 << 7, m0 = v0 & 31;
    const int b1 = v1 << 7, m1 = v1 & 31;
    const int b2 = v2 << 7, m2 = v2 & 31;
    const int bq = p << 7;
    float4 a0 = make_float4(0,0,0,0), a1 = a0, a2 = a0;
#pragma unroll
    for (int ci = 0; ci < 32; ++ci) {
        const float4 q4 = *(const float4*)&Qsw[bq + ((ci ^ p) << 2)];
        const float4 kA = *(const float4*)&Ksw[b0 + ((ci ^ m0) << 2)];
        const float4 kB = *(const float4*)&Ksw[b1 + ((ci ^ m1) << 2)];
        const float4 kC = *(const float4*)&Ksw[b2 + ((ci ^ m2) << 2)];
        a0.x += q4.x*kA.x; a0.y += q4.y*kA.y; a0.z += q4.z*kA.z; a0.w += q4.w*kA.w;
        a1.x += q4.x*kB.x; a1.y += q4.y*kB.y; a1.z += q4.z*kB.z; a1.w += q4.w*kB.w;
        a2.x += q4.x*kC.x; a2.y += q4.y*kC.y; a2.z += q4.z*kC.z; a2.w += q4.w*kC.w;
    }
    const float s0 = a0.x + a0.y + a0.z + a0.w;
    const float s1 = a1.x + a1.y + a1.z + a1.w;
    const float s2 = a2.x + a2.y + a2.z + a2.w;
    __syncthreads();   // B2: Ksw/Qsw dead, safe to overwrite

    // ---- restage ft into ftl[(r*16+xx)*128 + c] (zero-padded, quad-aligned)
    for (int e = t; e < 4608; e += 256) {           // 9 r x 128 c x 4 j
        const int j = e & 3, c = (e >> 2) & 127, r = e >> 9;
        const int gx0 = x0 - 4 + (j << 2);          // quad fully in or fully out
        const int gy = y + r - 4;
        float4 v = make_float4(0, 0, 0, 0);
        if ((unsigned)gy < 64u && (unsigned)gx0 < 64u)
            v = *(const float4*)&ft[(size_t)((nn * Cc + c) << 12) + (gy << 6) + gx0];
        const int base = ((r << 4) + (j << 2)) * 128 + c;
        ftl[base] = v.x; ftl[base + 128] = v.y; ftl[base + 256] = v.z; ftl[base + 384] = v.w;
    }

    // ---- softmax in registers: reduce over lanes sharing p (bits 3..5 of lane id)
    float m = fmaxf(s0, s1);
    if (has2) m = fmaxf(m, s2);
#pragma unroll
    for (int off = 8; off <= 32; off <<= 1) m = fmaxf(m, __shfl_xor(m, off));
    if ((t & 56) == 0) redM[((t >> 6) << 3) + p] = m;   // one lane per (wave, p)
    __syncthreads();   // B3 (also covers ftl writes)
    float mm = fmaxf(fmaxf(redM[p], redM[8 + p]), fmaxf(redM[16 + p], redM[24 + p]));
    const float e0 = __expf(s0 - mm);
    const float e1 = __expf(s1 - mm);
    const float e2 = has2 ? __expf(s2 - mm) : 0.f;
    simb[k0 * 8 + p] = e0;
    simb[k1 * 8 + p] = e1;
    if (has2) simb[(kb + 64) * 8 + p] = e2;
    float s = e0 + e1 + e2;
#pragma unroll
    for (int off = 8; off <= 32; off <<= 1) s += __shfl_xor(s, off);
    if ((t & 56) == 0) redS[((t >> 6) << 3) + p] = s;
    __syncthreads();   // B4
    const float inv = 1.f / (redS[p] + redS[8 + p] + redS[16 + p] + redS[24 + p]);

    // ---- weighting: thread = (p, cq); 4 channels per thread
    const int cq = t >> 3;
    float4 acc = make_float4(0, 0, 0, 0);
#pragma unroll
    for (int k = 0; k < KK; ++k) {
        const int r = k / 9, dx = k % 9;            // compile-time (unrolled)
        const float w = simb[k * 8 + p];            // 8-way broadcast: free
        const float4 f4 = *(const float4*)&ftl[((r << 4) + p + dx) * 128 + (cq << 2)];
        fma4(acc, f4, w);
    }
    const size_t ob = (size_t)((nn * Cc + (cq << 2)) << 12) + (y << 6) + x0 + p;
    out[ob]          = acc.x * inv;
    out[ob + HW]     = acc.y * inv;
    out[ob + 2*HW]   = acc.z * inv;
    out[ob + 3*HW]   = acc.w * inv;
}

extern "C" void kernel_launch(void* const* d_in, const int* in_sizes, int n_in,
                              void* d_out, int out_size, void* d_ws, size_t ws_size,
                              hipStream_t stream) {
    const float* ft = (const float*)d_in[0];
    const float* fk = (const float*)d_in[1];
    const float* Wm = (const float*)d_in[2];
    float* out = (float*)d_out;

    float* ws   = (float*)d_ws;          // 8 MB: Q(4MB) + K(4MB)
    float* Qbuf = ws;                    // [p][c]  8192*128
    float* Kbuf = ws + 1048576;          // [p][c]  8192*128

    proj_kernel<<<512, 256, 0, stream>>>(ft, fk, Wm, Qbuf, Kbuf);
    sim_weight_kernel<<<1024, 256, 0, stream>>>(Qbuf, Kbuf, ft, out);
}

// Round 6
// 141.453 us; speedup vs baseline: 1.0401x; 1.0401x over previous
//
#include <hip/hip_runtime.h>
#include <hip/hip_bf16.h>

// ILA layer (all fp32): key = W@ft, query = W@fk (1x1 conv, shared W),
// sim[p,k] = <query[p], key[neighbor_k(p)]> over 9x9 window (zero-padded keys),
// weight = softmax_k(sim)  (OOB entries participate with sim=0),
// out[c,p] = sum_k weight[k] * ft[c, neighbor_k(p)]  (zero-padded ft).
// n=2, c=128, h=w=64, L=9 (81 neighbors).

#define Hh 64
#define Ww 64
#define Cc 128
#define Nn 2
#define KK 81
#define HW (Hh * Ww)          // 4096
#define CHW (Cc * HW)         // 524288
#define P_TOT (Nn * HW)       // 8192

__device__ __forceinline__ void fma4(float4& a, const float4 b, const float s) {
    a.x += b.x * s; a.y += b.y * s; a.z += b.z * s; a.w += b.w * s;
}

// ---------------- Kernel A: projection (K = W*ft, Q = W*fk), pixel-major fp32 out.
// 256 blocks x 256 thr; 32 px/block; thread tile = 4 px x 4 out x {K,Q}.
// Per ii: 3 ds_read_b128 feed 32 FMAs (w4 8-lane-broadcast, k4/q4 8-lane-broadcast).
__global__ __launch_bounds__(256) void proj_kernel(const float* __restrict__ ft,
                                                   const float* __restrict__ fk,
                                                   const float* __restrict__ Wm,
                                                   float* __restrict__ Qbuf,
                                                   float* __restrict__ Kbuf) {
    __shared__ __align__(16) float Wl[32 * 132];   // [ii][o] chunk of W^T (banks shift 4/row)
    __shared__ __align__(16) float xkl[128 * 36];  // [i][pl]
    __shared__ __align__(16) float xql[128 * 36];
    const int t = threadIdx.x;
    const int p0 = blockIdx.x * 32;       // 4096 % 32 == 0: never crosses n
    const int nn = p0 >> 12;
    const int gbase = nn * CHW + (p0 & 4095);

    for (int e = t; e < 128 * 32; e += 256) {       // stage x tiles (coalesced 128B runs)
        const int c = e >> 5, pl = e & 31;
        xkl[c * 36 + pl] = ft[gbase + c * HW + pl];
        xql[c * 36 + pl] = fk[gbase + c * HW + pl];
    }

    const int po = t & 7;                 // 8 pixel groups x 4 px
    const int oo = t >> 3;                // 32 out groups x 4 out
    float4 accK[4], accQ[4];
#pragma unroll
    for (int i = 0; i < 4; ++i) { accK[i] = make_float4(0,0,0,0); accQ[i] = make_float4(0,0,0,0); }

    for (int ch = 0; ch < 4; ++ch) {
        for (int e = t; e < 128 * 32; e += 256) {   // Wl[ii][o] <- Wm[o][ch*32+ii]
            const int o = e >> 5, ii = e & 31;
            Wl[ii * 132 + o] = Wm[o * 128 + (ch << 5) + ii];
        }
        __syncthreads();
#pragma unroll 8
        for (int ii = 0; ii < 32; ++ii) {
            const int i = (ch << 5) + ii;
            const float4 w4 = *(const float4*)&Wl[ii * 132 + (oo << 2)];
            const float4 k4 = *(const float4*)&xkl[i * 36 + (po << 2)];
            const float4 q4 = *(const float4*)&xql[i * 36 + (po << 2)];
            fma4(accK[0], k4, w4.x); fma4(accK[1], k4, w4.y);
            fma4(accK[2], k4, w4.z); fma4(accK[3], k4, w4.w);
            fma4(accQ[0], q4, w4.x); fma4(accQ[1], q4, w4.y);
            fma4(accQ[2], q4, w4.z); fma4(accQ[3], q4, w4.w);
        }
        __syncthreads();
    }

    // register transpose -> px-major float4 stores (channels 4oo..4oo+3)
    const int pbase = p0 + (po << 2);
    const float4 vK0 = make_float4(accK[0].x, accK[1].x, accK[2].x, accK[3].x);
    const float4 vK1 = make_float4(accK[0].y, accK[1].y, accK[2].y, accK[3].y);
    const float4 vK2 = make_float4(accK[0].z, accK[1].z, accK[2].z, accK[3].z);
    const float4 vK3 = make_float4(accK[0].w, accK[1].w, accK[2].w, accK[3].w);
    const float4 vQ0 = make_float4(accQ[0].x, accQ[1].x, accQ[2].x, accQ[3].x);
    const float4 vQ1 = make_float4(accQ[0].y, accQ[1].y, accQ[2].y, accQ[3].y);
    const float4 vQ2 = make_float4(accQ[0].z, accQ[1].z, accQ[2].z, accQ[3].z);
    const float4 vQ3 = make_float4(accQ[0].w, accQ[1].w, accQ[2].w, accQ[3].w);
    *(float4*)&Kbuf[(size_t)(pbase    ) * 128 + (oo << 2)] = vK0;
    *(float4*)&Kbuf[(size_t)(pbase + 1) * 128 + (oo << 2)] = vK1;
    *(float4*)&Kbuf[(size_t)(pbase + 2) * 128 + (oo << 2)] = vK2;
    *(float4*)&Kbuf[(size_t)(pbase + 3) * 128 + (oo << 2)] = vK3;
    *(float4*)&Qbuf[(size_t)(pbase    ) * 128 + (oo << 2)] = vQ0;
    *(float4*)&Qbuf[(size_t)(pbase + 1) * 128 + (oo << 2)] = vQ1;
    *(float4*)&Qbuf[(size_t)(pbase + 2) * 128 + (oo << 2)] = vQ2;
    *(float4*)&Qbuf[(size_t)(pbase + 3) * 128 + (oo << 2)] = vQ3;
}

// ---------------- Kernel B (fused): sim + softmax + weighting. Block = 8-px row strip.
__global__ __launch_bounds__(256) void sim_weight_kernel(const float* __restrict__ Qbuf,
                                                         const float* __restrict__ Kbuf,
                                                         const float* __restrict__ ft,
                                                         float* __restrict__ out) {
    __shared__ __align__(16) float lds[20168];
    float* Ksw  = lds;            // 18432 floats (dead after dots)
    float* Qsw  = lds + 18432;    // 1024   (dead after dots)
    float* ftl  = lds;            // 19008 = 144 rows * 132 (aliases Ksw+Qsw after B2)
    float* redM = lds + 19456;    // 32
    float* redS = lds + 19488;    // 32
    float* simb = lds + 19520;    // 648

    const int t  = threadIdx.x;
    const int b  = blockIdx.x;
    const int x0 = (b & 7) << 3;
    const int y  = (b >> 3) & 63;
    const int nn = b >> 9;
    const int pg0 = (nn << 12) + (y << 6) + x0;

    // ---- stage K: zero-padded 9x16 window, XOR-swizzled float4 chunks
    for (int e = t; e < 144 * 32; e += 256) {
        const int v = e >> 5, ci = e & 31;
        const int gx = x0 + (v & 15) - 4;
        const int gy = y + (v >> 4) - 4;
        float4 val = make_float4(0, 0, 0, 0);
        if ((unsigned)gx < 64u && (unsigned)gy < 64u)
            val = *(const float4*)&Kbuf[(size_t)((nn << 12) + (gy << 6) + gx) * 128 + (ci << 2)];
        *(float4*)&Ksw[(v << 7) + (((ci ^ (v & 31)) << 2))] = val;
    }
    {   // stage Q: 8 vectors, 256 threads = exactly 8*32 chunks
        const int v = t >> 5, ci = t & 31;
        const float4 val = *(const float4*)&Qbuf[(size_t)(pg0 + v) * 128 + (ci << 2)];
        *(float4*)&Qsw[(v << 7) + ((ci ^ v) << 2)] = val;
    }
    __syncthreads();   // B1

    // ---- dots: thread -> (pixel p, k in {kb, kb+32, kb+64})
    const int p = t & 7, kb = t >> 3;
    const bool has2 = (kb + 64 < KK);
    const int k0 = kb, k1 = kb + 32, k2 = has2 ? kb + 64 : kb;
    const int v0 = (k0 / 9) * 16 + p + k0 % 9;
    const int v1 = (k1 / 9) * 16 + p + k1 % 9;
    const int v2 = (k2 / 9) * 16 + p + k2 % 9;
    const int b0 = v0 << 7, m0 = v0 & 31;
    const int b1 = v1 << 7, m1 = v1 & 31;
    const int b2 = v2 << 7, m2 = v2 & 31;
    const int bq = p << 7;
    float4 a0 = make_float4(0,0,0,0), a1 = a0, a2 = a0;
#pragma unroll
    for (int ci = 0; ci < 32; ++ci) {
        const float4 q4 = *(const float4*)&Qsw[bq + ((ci ^ p) << 2)];
        const float4 kA = *(const float4*)&Ksw[b0 + ((ci ^ m0) << 2)];
        const float4 kB = *(const float4*)&Ksw[b1 + ((ci ^ m1) << 2)];
        const float4 kC = *(const float4*)&Ksw[b2 + ((ci ^ m2) << 2)];
        a0.x += q4.x*kA.x; a0.y += q4.y*kA.y; a0.z += q4.z*kA.z; a0.w += q4.w*kA.w;
        a1.x += q4.x*kB.x; a1.y += q4.y*kB.y; a1.z += q4.z*kB.z; a1.w += q4.w*kB.w;
        a2.x += q4.x*kC.x; a2.y += q4.y*kC.y; a2.z += q4.z*kC.z; a2.w += q4.w*kC.w;
    }
    const float s0 = a0.x + a0.y + a0.z + a0.w;
    const float s1 = a1.x + a1.y + a1.z + a1.w;
    const float s2 = a2.x + a2.y + a2.z + a2.w;
    __syncthreads();   // B2: Ksw/Qsw dead, safe to overwrite

    // ---- restage ft into ftl[row*132 + c], row = r*16+xx (stride 132: staging
    // writes 2-way (free), weighting b128 reads at the structural bank floor)
    for (int e = t; e < 4608; e += 256) {           // 9 r x 128 c x 4 j
        const int j = e & 3, c = (e >> 2) & 127, r = e >> 9;
        const int gx0 = x0 - 4 + (j << 2);          // quad fully in or fully out
        const int gy = y + r - 4;
        float4 v = make_float4(0, 0, 0, 0);
        if ((unsigned)gy < 64u && (unsigned)gx0 < 64u)
            v = *(const float4*)&ft[(size_t)((nn * Cc + c) << 12) + (gy << 6) + gx0];
        const int base = ((r << 4) + (j << 2)) * 132 + c;
        ftl[base] = v.x; ftl[base + 132] = v.y; ftl[base + 264] = v.z; ftl[base + 396] = v.w;
    }

    // ---- softmax in registers: reduce over lanes sharing p (bits 3..5 of lane id)
    float m = fmaxf(s0, s1);
    if (has2) m = fmaxf(m, s2);
#pragma unroll
    for (int off = 8; off <= 32; off <<= 1) m = fmaxf(m, __shfl_xor(m, off));
    if ((t & 56) == 0) redM[((t >> 6) << 3) + p] = m;   // one lane per (wave, p)
    __syncthreads();   // B3 (also covers ftl writes)
    float mm = fmaxf(fmaxf(redM[p], redM[8 + p]), fmaxf(redM[16 + p], redM[24 + p]));
    const float e0 = __expf(s0 - mm);
    const float e1 = __expf(s1 - mm);
    const float e2 = has2 ? __expf(s2 - mm) : 0.f;
    simb[k0 * 8 + p] = e0;
    simb[k1 * 8 + p] = e1;
    if (has2) simb[(kb + 64) * 8 + p] = e2;
    float s = e0 + e1 + e2;
#pragma unroll
    for (int off = 8; off <= 32; off <<= 1) s += __shfl_xor(s, off);
    if ((t & 56) == 0) redS[((t >> 6) << 3) + p] = s;
    __syncthreads();   // B4
    const float inv = 1.f / (redS[p] + redS[8 + p] + redS[16 + p] + redS[24 + p]);

    // ---- weighting: thread = (p, cq); 4 channels per thread.
    // r rolled, dx unrolled 9: <=~40 live VGPRs (vs 81-deep full unroll -> spills)
    const int cq = t >> 3;
    float4 acc = make_float4(0, 0, 0, 0);
    for (int r = 0; r < 9; ++r) {
        const int rb = ((r << 4) + p) * 132 + (cq << 2);
        const int k9 = r * 9;
#pragma unroll
        for (int dx = 0; dx < 9; ++dx) {
            const float w = simb[(k9 + dx) * 8 + p];    // 8-lane broadcast
            const float4 f4 = *(const float4*)&ftl[rb + dx * 132];
            fma4(acc, f4, w);
        }
    }
    const size_t ob = (size_t)((nn * Cc + (cq << 2)) << 12) + (y << 6) + x0 + p;
    out[ob]          = acc.x * inv;
    out[ob + HW]     = acc.y * inv;
    out[ob + 2*HW]   = acc.z * inv;
    out[ob + 3*HW]   = acc.w * inv;
}

extern "C" void kernel_launch(void* const* d_in, const int* in_sizes, int n_in,
                              void* d_out, int out_size, void* d_ws, size_t ws_size,
                              hipStream_t stream) {
    const float* ft = (const float*)d_in[0];
    const float* fk = (const float*)d_in[1];
    const float* Wm = (const float*)d_in[2];
    float* out = (float*)d_out;

    float* ws   = (float*)d_ws;          // 8 MB: Q(4MB) + K(4MB)
    float* Qbuf = ws;                    // [p][c]  8192*128
    float* Kbuf = ws + 1048576;          // [p][c]  8192*128

    proj_kernel<<<256, 256, 0, stream>>>(ft, fk, Wm, Qbuf, Kbuf);
    sim_weight_kernel<<<1024, 256, 0, stream>>>(Qbuf, Kbuf, ft, out);
}

// Round 7
// 108.588 us; speedup vs baseline: 1.3549x; 1.3027x over previous
//
#include <hip/hip_runtime.h>
#include <hip/hip_bf16.h>

// ILA layer (all fp32): key = W@ft, query = W@fk (1x1 conv, shared W),
// sim[p,k] = <query[p], key[neighbor_k(p)]> over 9x9 window (zero-padded keys),
// weight = softmax_k(sim)  (OOB entries participate with sim=0),
// out[c,p] = sum_k weight[k] * ft[c, neighbor_k(p)]  (zero-padded ft).
// n=2, c=128, h=w=64, L=9 (81 neighbors).

#define Hh 64
#define Ww 64
#define Cc 128
#define Nn 2
#define KK 81
#define HW (Hh * Ww)          // 4096
#define CHW (Cc * HW)         // 524288
#define P_TOT (Nn * HW)       // 8192

__device__ __forceinline__ void fma4(float4& a, const float4 b, const float s) {
    a.x += b.x * s; a.y += b.y * s; a.z += b.z * s; a.w += b.w * s;
}

// ---------------- Kernel A: projection (K = W*ft, Q = W*fk), pixel-major fp32 out.
// 256 blocks x 256 thr; 32 px/block; thread tile = 4 px x 4 out x {K,Q}.
__global__ __launch_bounds__(256) void proj_kernel(const float* __restrict__ ft,
                                                   const float* __restrict__ fk,
                                                   const float* __restrict__ Wm,
                                                   float* __restrict__ Qbuf,
                                                   float* __restrict__ Kbuf) {
    __shared__ __align__(16) float Wl[32 * 132];   // [ii][o] chunk of W^T
    __shared__ __align__(16) float xkl[128 * 36];  // [i][pl]
    __shared__ __align__(16) float xql[128 * 36];
    const int t = threadIdx.x;
    const int p0 = blockIdx.x * 32;       // 4096 % 32 == 0: never crosses n
    const int nn = p0 >> 12;
    const int gbase = nn * CHW + (p0 & 4095);

    for (int e = t; e < 128 * 32; e += 256) {       // stage x tiles (coalesced 128B runs)
        const int c = e >> 5, pl = e & 31;
        xkl[c * 36 + pl] = ft[gbase + c * HW + pl];
        xql[c * 36 + pl] = fk[gbase + c * HW + pl];
    }

    const int po = t & 7;                 // 8 pixel groups x 4 px
    const int oo = t >> 3;                // 32 out groups x 4 out
    float4 accK[4], accQ[4];
#pragma unroll
    for (int i = 0; i < 4; ++i) { accK[i] = make_float4(0,0,0,0); accQ[i] = make_float4(0,0,0,0); }

    for (int ch = 0; ch < 4; ++ch) {
        for (int e = t; e < 128 * 32; e += 256) {   // Wl[ii][o] <- Wm[o][ch*32+ii]
            const int o = e >> 5, ii = e & 31;
            Wl[ii * 132 + o] = Wm[o * 128 + (ch << 5) + ii];
        }
        __syncthreads();
#pragma unroll 4
        for (int ii = 0; ii < 32; ++ii) {
            const int i = (ch << 5) + ii;
            const float4 w4 = *(const float4*)&Wl[ii * 132 + (oo << 2)];
            const float4 k4 = *(const float4*)&xkl[i * 36 + (po << 2)];
            const float4 q4 = *(const float4*)&xql[i * 36 + (po << 2)];
            fma4(accK[0], k4, w4.x); fma4(accK[1], k4, w4.y);
            fma4(accK[2], k4, w4.z); fma4(accK[3], k4, w4.w);
            fma4(accQ[0], q4, w4.x); fma4(accQ[1], q4, w4.y);
            fma4(accQ[2], q4, w4.z); fma4(accQ[3], q4, w4.w);
        }
        __syncthreads();
    }

    // register transpose -> px-major float4 stores (channels 4oo..4oo+3)
    const int pbase = p0 + (po << 2);
    const float4 vK0 = make_float4(accK[0].x, accK[1].x, accK[2].x, accK[3].x);
    const float4 vK1 = make_float4(accK[0].y, accK[1].y, accK[2].y, accK[3].y);
    const float4 vK2 = make_float4(accK[0].z, accK[1].z, accK[2].z, accK[3].z);
    const float4 vK3 = make_float4(accK[0].w, accK[1].w, accK[2].w, accK[3].w);
    const float4 vQ0 = make_float4(accQ[0].x, accQ[1].x, accQ[2].x, accQ[3].x);
    const float4 vQ1 = make_float4(accQ[0].y, accQ[1].y, accQ[2].y, accQ[3].y);
    const float4 vQ2 = make_float4(accQ[0].z, accQ[1].z, accQ[2].z, accQ[3].z);
    const float4 vQ3 = make_float4(accQ[0].w, accQ[1].w, accQ[2].w, accQ[3].w);
    *(float4*)&Kbuf[(size_t)(pbase    ) * 128 + (oo << 2)] = vK0;
    *(float4*)&Kbuf[(size_t)(pbase + 1) * 128 + (oo << 2)] = vK1;
    *(float4*)&Kbuf[(size_t)(pbase + 2) * 128 + (oo << 2)] = vK2;
    *(float4*)&Kbuf[(size_t)(pbase + 3) * 128 + (oo << 2)] = vK3;
    *(float4*)&Qbuf[(size_t)(pbase    ) * 128 + (oo << 2)] = vQ0;
    *(float4*)&Qbuf[(size_t)(pbase + 1) * 128 + (oo << 2)] = vQ1;
    *(float4*)&Qbuf[(size_t)(pbase + 2) * 128 + (oo << 2)] = vQ2;
    *(float4*)&Qbuf[(size_t)(pbase + 3) * 128 + (oo << 2)] = vQ3;
}

// ---------------- Kernel B (fused): sim + softmax + weighting. Block = 8-px row strip.
// Unrolls capped so per-phase VGPR demand stays well under 256 (round-6 spill fix).
__global__ __launch_bounds__(256, 2) void sim_weight_kernel(const float* __restrict__ Qbuf,
                                                            const float* __restrict__ Kbuf,
                                                            const float* __restrict__ ft,
                                                            float* __restrict__ out) {
    __shared__ __align__(16) float lds[20168];
    float* Ksw  = lds;            // 18432 floats (dead after dots)
    float* Qsw  = lds + 18432;    // 1024   (dead after dots)
    float* ftl  = lds;            // 19008 = 144 rows * 132 (aliases Ksw+Qsw after B2)
    float* redM = lds + 19456;    // 32
    float* redS = lds + 19488;    // 32
    float* simb = lds + 19520;    // 648

    const int t  = threadIdx.x;
    const int b  = blockIdx.x;
    const int x0 = (b & 7) << 3;
    const int y  = (b >> 3) & 63;
    const int nn = b >> 9;
    const int pg0 = (nn << 12) + (y << 6) + x0;

    // ---- stage K: zero-padded 9x16 window, XOR-swizzled float4 chunks
#pragma unroll 2
    for (int e = t; e < 144 * 32; e += 256) {
        const int v = e >> 5, ci = e & 31;
        const int gx = x0 + (v & 15) - 4;
        const int gy = y + (v >> 4) - 4;
        float4 val = make_float4(0, 0, 0, 0);
        if ((unsigned)gx < 64u && (unsigned)gy < 64u)
            val = *(const float4*)&Kbuf[(size_t)((nn << 12) + (gy << 6) + gx) * 128 + (ci << 2)];
        *(float4*)&Ksw[(v << 7) + (((ci ^ (v & 31)) << 2))] = val;
    }
    {   // stage Q: 8 vectors, 256 threads = exactly 8*32 chunks
        const int v = t >> 5, ci = t & 31;
        const float4 val = *(const float4*)&Qbuf[(size_t)(pg0 + v) * 128 + (ci << 2)];
        *(float4*)&Qsw[(v << 7) + ((ci ^ v) << 2)] = val;
    }
    __syncthreads();   // B1

    // ---- dots: thread -> (pixel p, k in {kb, kb+32, kb+64})
    const int p = t & 7, kb = t >> 3;
    const bool has2 = (kb + 64 < KK);
    const int k0 = kb, k1 = kb + 32, k2 = has2 ? kb + 64 : kb;
    const int v0 = (k0 / 9) * 16 + p + k0 % 9;
    const int v1 = (k1 / 9) * 16 + p + k1 % 9;
    const int v2 = (k2 / 9) * 16 + p + k2 % 9;
    const int b0 = v0 << 7, m0 = v0 & 31;
    const int b1 = v1 << 7, m1 = v1 & 31;
    const int b2 = v2 << 7, m2 = v2 & 31;
    const int bq = p << 7;
    float4 a0 = make_float4(0,0,0,0), a1 = a0, a2 = a0;
#pragma unroll 4
    for (int ci = 0; ci < 32; ++ci) {
        const float4 q4 = *(const float4*)&Qsw[bq + ((ci ^ p) << 2)];
        const float4 kA = *(const float4*)&Ksw[b0 + ((ci ^ m0) << 2)];
        const float4 kB = *(const float4*)&Ksw[b1 + ((ci ^ m1) << 2)];
        const float4 kC = *(const float4*)&Ksw[b2 + ((ci ^ m2) << 2)];
        a0.x += q4.x*kA.x; a0.y += q4.y*kA.y; a0.z += q4.z*kA.z; a0.w += q4.w*kA.w;
        a1.x += q4.x*kB.x; a1.y += q4.y*kB.y; a1.z += q4.z*kB.z; a1.w += q4.w*kB.w;
        a2.x += q4.x*kC.x; a2.y += q4.y*kC.y; a2.z += q4.z*kC.z; a2.w += q4.w*kC.w;
    }
    const float s0 = a0.x + a0.y + a0.z + a0.w;
    const float s1 = a1.x + a1.y + a1.z + a1.w;
    const float s2 = a2.x + a2.y + a2.z + a2.w;
    __syncthreads();   // B2: Ksw/Qsw dead, safe to overwrite

    // ---- restage ft into ftl[row*132 + c], row = r*16+xx (stride 132: staging
    // writes 2-way (free), weighting b128 reads at the structural bank floor)
#pragma unroll 2
    for (int e = t; e < 4608; e += 256) {           // 9 r x 128 c x 4 j
        const int j = e & 3, c = (e >> 2) & 127, r = e >> 9;
        const int gx0 = x0 - 4 + (j << 2);          // quad fully in or fully out
        const int gy = y + r - 4;
        float4 v = make_float4(0, 0, 0, 0);
        if ((unsigned)gy < 64u && (unsigned)gx0 < 64u)
            v = *(const float4*)&ft[(size_t)((nn * Cc + c) << 12) + (gy << 6) + gx0];
        const int base = ((r << 4) + (j << 2)) * 132 + c;
        ftl[base] = v.x; ftl[base + 132] = v.y; ftl[base + 264] = v.z; ftl[base + 396] = v.w;
    }

    // ---- softmax in registers: reduce over lanes sharing p (bits 3..5 of lane id)
    float m = fmaxf(s0, s1);
    if (has2) m = fmaxf(m, s2);
#pragma unroll
    for (int off = 8; off <= 32; off <<= 1) m = fmaxf(m, __shfl_xor(m, off));
    if ((t & 56) == 0) redM[((t >> 6) << 3) + p] = m;   // one lane per (wave, p)
    __syncthreads();   // B3 (also covers ftl writes)
    float mm = fmaxf(fmaxf(redM[p], redM[8 + p]), fmaxf(redM[16 + p], redM[24 + p]));
    const float e0 = __expf(s0 - mm);
    const float e1 = __expf(s1 - mm);
    const float e2 = has2 ? __expf(s2 - mm) : 0.f;
    simb[k0 * 8 + p] = e0;
    simb[k1 * 8 + p] = e1;
    if (has2) simb[(kb + 64) * 8 + p] = e2;
    float s = e0 + e1 + e2;
#pragma unroll
    for (int off = 8; off <= 32; off <<= 1) s += __shfl_xor(s, off);
    if ((t & 56) == 0) redS[((t >> 6) << 3) + p] = s;
    __syncthreads();   // B4
    const float inv = 1.f / (redS[p] + redS[8 + p] + redS[16 + p] + redS[24 + p]);

    // ---- weighting: thread = (p, cq); 4 channels per thread.
    const int cq = t >> 3;
    float4 acc = make_float4(0, 0, 0, 0);
    for (int r = 0; r < 9; ++r) {
        const int rb = ((r << 4) + p) * 132 + (cq << 2);
        const int k9 = r * 9;
#pragma unroll 3
        for (int dx = 0; dx < 9; ++dx) {
            const float w = simb[(k9 + dx) * 8 + p];    // 8-lane broadcast
            const float4 f4 = *(const float4*)&ftl[rb + dx * 132];
            fma4(acc, f4, w);
        }
    }
    const size_t ob = (size_t)((nn * Cc + (cq << 2)) << 12) + (y << 6) + x0 + p;
    out[ob]          = acc.x * inv;
    out[ob + HW]     = acc.y * inv;
    out[ob + 2*HW]   = acc.z * inv;
    out[ob + 3*HW]   = acc.w * inv;
}

extern "C" void kernel_launch(void* const* d_in, const int* in_sizes, int n_in,
                              void* d_out, int out_size, void* d_ws, size_t ws_size,
                              hipStream_t stream) {
    const float* ft = (const float*)d_in[0];
    const float* fk = (const float*)d_in[1];
    const float* Wm = (const float*)d_in[2];
    float* out = (float*)d_out;

    float* ws   = (float*)d_ws;          // 8 MB: Q(4MB) + K(4MB)
    float* Qbuf = ws;                    // [p][c]  8192*128
    float* Kbuf = ws + 1048576;          // [p][c]  8192*128

    proj_kernel<<<256, 256, 0, stream>>>(ft, fk, Wm, Qbuf, Kbuf);
    sim_weight_kernel<<<1024, 256, 0, stream>>>(Qbuf, Kbuf, ft, out);
}